// Round 5
// baseline (391.402 us; speedup 1.0000x reference)
//
#include <hip/hip_runtime.h>
#include <stdint.h>

// Each 64x64 matrix: bf16 planes in LDS, unpadded stride 64, XOR-swizzled:
//   element [r][c] at short-index  r*64 + (((c>>3) ^ (r&7))<<3) + (c&7)
//   R-plane: row-major (MFMA A-fragment = one b128)
//   T-plane: transposed (MFMA B-fragment = one b128)
// 6 fixed plane slots (periodic schedule), all LDS addrs = invariant reg+imm.
#define PL 4096  // shorts per plane

typedef unsigned int u32;
typedef unsigned short u16;
typedef float f32x4 __attribute__((ext_vector_type(4)));
typedef short short8 __attribute__((ext_vector_type(8)));

__device__ __forceinline__ u32 prm(u32 a, u32 b, u32 s) {
  return __builtin_amdgcn_perm(a, b, s);
}
__device__ __forceinline__ u32 pk(float f0, float f1) {  // {bf16 f0, bf16 f1}
  return prm(__float_as_uint(f1), __float_as_uint(f0), 0x07060302u);
}
__device__ __forceinline__ float rlo(u32 w) { return __uint_as_float(w << 16); }
__device__ __forceinline__ float rhi(u32 w) {
  return __uint_as_float(w & 0xffff0000u);
}

// Per-thread invariant LDS short-offsets.
struct O {
  int ra[2][2];  // A-frag read [ti][q]  (row-tile a = 2*wv+ti)
  int rb[4][2];  // B-frag read [tj][q]
  int sT[2][4];  // T-plane store for primary acc[ti][tj]
  int sR[2][4];  // R-plane store for mirror product of tile (ti,tj)
  int prow[4];   // patch row reads/writes: sidx(r0+i, c0), 8-elem run
  int pcol[8];   // patch col writes: sidx(c0+j, r0), 4-elem run
};

// C = A @ B (64x64 bf16). 2 waves: wave wv owns rows 32*wv (2 row-tiles x 4
// col-tiles of 16x16). Primary product -> T-plane (D is C^T-contiguous);
// mirrored product (operands swapped) -> R-plane. WR/WT gate dead planes.
// Dest planes != source planes. Trailing barrier.
template <bool WR, bool WT>
__device__ __forceinline__ void mm(const u16* __restrict__ AR,
                                   const u16* __restrict__ BT,
                                   u16* __restrict__ CR, u16* __restrict__ CT,
                                   const O& o) {
  short8 a0[2], a1[2], b0[4], b1[4];
#pragma unroll
  for (int t = 0; t < 2; ++t) {
    a0[t] = *(const short8*)(AR + o.ra[t][0]);
    a1[t] = *(const short8*)(AR + o.ra[t][1]);
  }
#pragma unroll
  for (int t = 0; t < 4; ++t) {
    b0[t] = *(const short8*)(BT + o.rb[t][0]);
    b1[t] = *(const short8*)(BT + o.rb[t][1]);
  }
  const f32x4 Z = {0.0f, 0.0f, 0.0f, 0.0f};
#pragma unroll
  for (int ti = 0; ti < 2; ++ti)
#pragma unroll
    for (int tj = 0; tj < 4; ++tj) {
      if (WT) {
        f32x4 acc = __builtin_amdgcn_mfma_f32_16x16x32_bf16(a0[ti], b0[tj], Z,
                                                            0, 0, 0);
        acc = __builtin_amdgcn_mfma_f32_16x16x32_bf16(a1[ti], b1[tj], acc, 0,
                                                      0, 0);
        *(uint2*)(CT + o.sT[ti][tj]) =
            make_uint2(pk(acc[0], acc[1]), pk(acc[2], acc[3]));
      }
      if (WR) {
        f32x4 acc = __builtin_amdgcn_mfma_f32_16x16x32_bf16(b0[tj], a0[ti], Z,
                                                            0, 0, 0);
        acc = __builtin_amdgcn_mfma_f32_16x16x32_bf16(b1[tj], a1[ti], acc, 0,
                                                      0, 0);
        *(uint2*)(CR + o.sR[ti][tj]) =
            make_uint2(pk(acc[0], acc[1]), pk(acc[2], acc[3]));
      }
    }
  __syncthreads();
}

// One block (128 thr = 2 waves) per batch element. Thread owns a 4x8 patch
// (r0 = (tid&15)*4, c0 = (tid>>4)*8) for all elementwise work.
//
// Plane usage analysis (R = used as left operand, T = as right/transposed):
//   m both | m2 R | m3 both | m6 both | m12 R | m15 both(+trace) | m30 both
//   | m60 R | m63 T(grad). Carried across iters: R15,T15,T3.
// Periodic 6-slot schedule (PA..PF), invariant {PA=R15, PB=T15, PC=T3}:
//   m30: (PA,PB)->PD,PE   m60: (PD,PE)->PA[R]   m63: (PA,PC)->PB[T]
//   grad/prox; stage m->PD,PE
//   m2: (PD,PE)->PF[R]    m3: (PF,PE)->PA,PC    m6: (PA,PC)->PD,PE
//   m12: (PD,PE)->PF[R]   m15: (PF,PC)->PA,PB   trace = sum R15.*T15
__global__ __launch_bounds__(128, 1) void dag_iter_kernel(
    const float* __restrict__ adj, float* __restrict__ out, int niter) {
  __shared__ __align__(16) u16 BUF[6 * PL];
  __shared__ float red[2];
  u16* PA = BUF;
  u16* PB = BUF + PL;
  u16* PC = BUF + 2 * PL;
  u16* PD = BUF + 3 * PL;
  u16* PE = BUF + 4 * PL;
  u16* PF = BUF + 5 * PL;

  const int tid = (int)threadIdx.x;
  const int lane = tid & 63;
  const int wv = tid >> 6;
  const int l15 = lane & 15;
  const int grp = lane >> 4;
  const int l7 = l15 & 7;
  const int r0 = (tid & 15) << 2;
  const int c0 = (tid >> 4) << 3;

  O o;
#pragma unroll
  for (int q = 0; q < 2; ++q) {
    const int koff = (((q << 2) + grp) ^ l7) << 3;
#pragma unroll
    for (int ti = 0; ti < 2; ++ti)
      o.ra[ti][q] = (16 * (2 * wv + ti) + l15) * 64 + koff;
#pragma unroll
    for (int tj = 0; tj < 4; ++tj)
      o.rb[tj][q] = (16 * tj + l15) * 64 + koff;
  }
  // addr(a,b): store loc for product tile rows 16a, col-run 16b+4*grp
#pragma unroll
  for (int ti = 0; ti < 2; ++ti)
#pragma unroll
    for (int tj = 0; tj < 4; ++tj) {
      const int a = 2 * wv + ti;
      o.sT[ti][tj] = (16 * tj + l15) * 64 +
                     (((2 * a + (grp >> 1)) ^ l7) << 3) + ((grp & 1) << 2);
      o.sR[ti][tj] = (16 * a + l15) * 64 +
                     (((2 * tj + (grp >> 1)) ^ l7) << 3) + ((grp & 1) << 2);
    }
#pragma unroll
  for (int i = 0; i < 4; ++i)
    o.prow[i] = (r0 + i) * 64 + ((((c0 >> 3) ^ ((r0 + i) & 7))) << 3);
#pragma unroll
  for (int j = 0; j < 8; ++j)
    o.pcol[j] = (c0 + j) * 64 + (((r0 >> 3) ^ ((c0 + j) & 7)) << 3) + (r0 & 7);

  const float* src = adj + (size_t)blockIdx.x * 4096;
  float x[4][8], sc[4][8];
#pragma unroll
  for (int i = 0; i < 4; ++i) {
    f32x4 v0 = *(const f32x4*)(src + (r0 + i) * 64 + c0);
    f32x4 v1 = *(const f32x4*)(src + (r0 + i) * 64 + c0 + 4);
#pragma unroll
    for (int j = 0; j < 4; ++j) {
      x[i][j] = v0[j];
      x[i][j + 4] = v1[j];
    }
#pragma unroll
    for (int j = 0; j < 8; ++j) sc[i][j] = (x[i][j] > 0.5f) ? x[i][j] : 0.0f;
  }
  float alpha = 0.0f;

  // ---- helpers as lambdas ----
  auto prox = [&](float til[4][8]) {
#pragma unroll
    for (int i = 0; i < 4; ++i)
#pragma unroll
      for (int j = 0; j < 8; ++j) {
        float ax = fabsf(til[i][j]) - 2e-5f;
        float nx = ax > 0.0f ? ax : 0.0f;
        x[i][j] = nx > 1.0f ? 1.0f : nx;
      }
  };
  auto stage = [&](u16* R, u16* T) {  // m = I + x.*x/64 -> both planes
    float m[4][8];
#pragma unroll
    for (int i = 0; i < 4; ++i)
#pragma unroll
      for (int j = 0; j < 8; ++j)
        m[i][j] = fmaf(x[i][j] * x[i][j], 0.015625f,
                       (r0 + i == c0 + j) ? 1.0f : 0.0f);
#pragma unroll
    for (int i = 0; i < 4; ++i) {
      int4 v;
      v.x = (int)pk(m[i][0], m[i][1]);
      v.y = (int)pk(m[i][2], m[i][3]);
      v.z = (int)pk(m[i][4], m[i][5]);
      v.w = (int)pk(m[i][6], m[i][7]);
      *(int4*)(R + o.prow[i]) = v;
    }
#pragma unroll
    for (int j = 0; j < 8; ++j)
      *(uint2*)(T + o.pcol[j]) =
          make_uint2(pk(m[0][j], m[1][j]), pk(m[2][j], m[3][j]));
    __syncthreads();
  };
  auto chain5 = [&]() {  // stage already done into PD,PE
    mm<true, false>(PD, PE, PF, PF, o);  // m2  -> R only
    mm<true, true>(PF, PE, PA, PC, o);   // m3  = m2*m
    mm<true, true>(PA, PC, PD, PE, o);   // m6  = m3^2
    mm<true, false>(PD, PE, PF, PF, o);  // m12 -> R only
    mm<true, true>(PF, PC, PA, PB, o);   // m15 = m12*m3
    // trace(m^30) = sum_elem R15 .* T15 (identical swizzled addressing)
    float part = 0.0f;
#pragma unroll
    for (int i = 0; i < 4; ++i) {
      int4 a = *(const int4*)(PA + o.prow[i]);
      int4 b = *(const int4*)(PB + o.prow[i]);
      const u32* ap = (const u32*)&a;
      const u32* bp = (const u32*)&b;
#pragma unroll
      for (int w = 0; w < 4; ++w) {
        part = fmaf(rlo(ap[w]), rlo(bp[w]), part);
        part = fmaf(rhi(ap[w]), rhi(bp[w]), part);
      }
    }
#pragma unroll
    for (int off = 32; off > 0; off >>= 1) part += __shfl_down(part, off);
    if (lane == 0) red[wv] = part;
    // visibility: consumed after >=1 barrier (next iter's m30..m63)
  };
  auto gradprox = [&]() {  // uses T63 in PB; updates alpha from red[]
    float tr = red[0] + red[1];
    alpha = fmaf(0.01f, tr * 0.015625f - 1.0f, alpha);
    const float a2 = alpha * 0.03125f;  // 2*alpha/64
    float til[4][8];
#pragma unroll
    for (int i = 0; i < 4; ++i) {
      int4 w = *(const int4*)(PB + o.prow[i]);
      const u32* wp = (const u32*)&w;
#pragma unroll
      for (int j = 0; j < 4; ++j) {
        float ptA = rlo(wp[j]);
        float ptB = rhi(wp[j]);
        float gA = fmaf(a2 * x[i][2 * j], ptA, -sc[i][2 * j]);
        float gB = fmaf(a2 * x[i][2 * j + 1], ptB, -sc[i][2 * j + 1]);
        til[i][2 * j] = fmaf(-0.01f, gA, x[i][2 * j]);
        til[i][2 * j + 1] = fmaf(-0.01f, gB, x[i][2 * j + 1]);
      }
    }
    prox(til);
  };

  // ---- iteration 0: alpha == 0 -> grad = -scores ----
  {
    float til[4][8];
#pragma unroll
    for (int i = 0; i < 4; ++i)
#pragma unroll
      for (int j = 0; j < 8; ++j) til[i][j] = fmaf(0.01f, sc[i][j], x[i][j]);
    prox(til);
    stage(PD, PE);
    chain5();
  }
  // ---- iterations 1..48 ----
  for (int it = 0; it < 48; ++it) {
    mm<true, true>(PA, PB, PD, PE, o);   // m30 = m15^2
    mm<true, false>(PD, PE, PA, PA, o);  // m60 -> R only
    mm<false, true>(PA, PC, PB, PB, o);  // m63 = m60*m3 -> T only
    gradprox();
    stage(PD, PE);
    chain5();
  }
  // ---- iteration 49: no trailing trace chain ----
  mm<true, true>(PA, PB, PD, PE, o);
  mm<true, false>(PD, PE, PA, PA, o);
  mm<false, true>(PA, PC, PB, PB, o);
  gradprox();

  float* dst = out + (size_t)blockIdx.x * 4096;
#pragma unroll
  for (int i = 0; i < 4; ++i) {
    f32x4 v0, v1;
#pragma unroll
    for (int j = 0; j < 4; ++j) {
      v0[j] = (x[i][j] > 0.5f) ? x[i][j] : 0.0f;
      v1[j] = (x[i][j + 4] > 0.5f) ? x[i][j + 4] : 0.0f;
    }
    *(f32x4*)(dst + (r0 + i) * 64 + c0) = v0;
    *(f32x4*)(dst + (r0 + i) * 64 + c0 + 4) = v1;
  }
}

extern "C" void kernel_launch(void* const* d_in, const int* in_sizes, int n_in,
                              void* d_out, int out_size, void* d_ws,
                              size_t ws_size, hipStream_t stream) {
  const float* adj = (const float*)d_in[0];
  float* out = (float*)d_out;
  const int nbatch = in_sizes[0] / 4096;  // 512
  dag_iter_kernel<<<nbatch, 128, 0, stream>>>(adj, out, 50);
}

// Round 6
// 292.270 us; speedup vs baseline: 1.3392x; 1.3392x over previous
//
#include <hip/hip_runtime.h>
#include <stdint.h>

// Each 64x64 matrix: bf16 planes in LDS, unpadded stride 64, XOR-swizzled:
//   element [r][c] at short-index  r*64 + (((c>>3) ^ (r&7))<<3) + (c&7)
//   R-plane: row-major (MFMA A-fragment = one b128)
//   T-plane: transposed (MFMA B-fragment = one b128)
// 6 fixed plane slots (periodic schedule); all LDS addrs loop-invariant.
#define PL 4096  // shorts per plane

typedef unsigned int u32;
typedef unsigned short u16;
typedef float f32x4 __attribute__((ext_vector_type(4)));
typedef short short8 __attribute__((ext_vector_type(8)));

__device__ __forceinline__ u32 prm(u32 a, u32 b, u32 s) {
  return __builtin_amdgcn_perm(a, b, s);
}
__device__ __forceinline__ u32 pk(float f0, float f1) {  // {bf16 f0, bf16 f1}
  return prm(__float_as_uint(f1), __float_as_uint(f0), 0x07060302u);
}
__device__ __forceinline__ float rlo(u32 w) { return __uint_as_float(w << 16); }
__device__ __forceinline__ float rhi(u32 w) {
  return __uint_as_float(w & 0xffff0000u);
}

// Per-thread invariant LDS short-offsets (4-wave 2x2 quadrant split).
struct O {
  int ra[2][2];  // A-frag read [ti][q]
  int rb[2][2];  // B-frag read [tj][q]
  int sT[2][2];  // T-plane store for primary product tile (ti,tj)
  int sR[2][2];  // R-plane store for mirror product tile (ti,tj)
  int prow[4];   // patch addr: sidx(r0+i, c0), 4-elem run
  int pcol[4];   // patch addr: sidx(c0+j, r0), 4-elem run
};

// C = A @ B (64x64 bf16). 4 waves: wave wv owns quadrant (rh,ch) as 2x2
// 16x16 tiles. Primary product (a x b) -> D is C^T-contiguous -> T-plane;
// mirror product (b x a) -> C-contiguous -> R-plane. WR/WT gate dead planes
// (gated rounds skip that product's MFMAs, packs, and stores entirely).
// Dest planes != source planes. Trailing barrier.
template <bool WR, bool WT>
__device__ __forceinline__ void mm(const u16* __restrict__ AR,
                                   const u16* __restrict__ BT,
                                   u16* __restrict__ CR, u16* __restrict__ CT,
                                   const O& o) {
  short8 a0[2], a1[2], b0[2], b1[2];
#pragma unroll
  for (int t = 0; t < 2; ++t) {
    a0[t] = *(const short8*)(AR + o.ra[t][0]);
    a1[t] = *(const short8*)(AR + o.ra[t][1]);
    b0[t] = *(const short8*)(BT + o.rb[t][0]);
    b1[t] = *(const short8*)(BT + o.rb[t][1]);
  }
  const f32x4 Z = {0.0f, 0.0f, 0.0f, 0.0f};
#pragma unroll
  for (int ti = 0; ti < 2; ++ti)
#pragma unroll
    for (int tj = 0; tj < 2; ++tj) {
      if (WT) {
        f32x4 acc = __builtin_amdgcn_mfma_f32_16x16x32_bf16(a0[ti], b0[tj], Z,
                                                            0, 0, 0);
        acc = __builtin_amdgcn_mfma_f32_16x16x32_bf16(a1[ti], b1[tj], acc, 0,
                                                      0, 0);
        *(uint2*)(CT + o.sT[ti][tj]) =
            make_uint2(pk(acc[0], acc[1]), pk(acc[2], acc[3]));
      }
      if (WR) {
        f32x4 acc = __builtin_amdgcn_mfma_f32_16x16x32_bf16(b0[tj], a0[ti], Z,
                                                            0, 0, 0);
        acc = __builtin_amdgcn_mfma_f32_16x16x32_bf16(b1[tj], a1[ti], acc, 0,
                                                      0, 0);
        *(uint2*)(CR + o.sR[ti][tj]) =
            make_uint2(pk(acc[0], acc[1]), pk(acc[2], acc[3]));
      }
    }
  __syncthreads();
}

// One block (256 thr = 4 waves) per batch element. Thread owns a 4x4 patch
// (r0 = (tid&15)*4, c0 = (tid>>4)*4) for elementwise work.
//
// Plane usage (R = needed as left operand, T = as right/transposed):
//   m both | m2 R | m3 both | m6 both | m12 R | m15 both(+trace) | m30 both
//   | m60 R | m63 T(grad). Carried across iters: R15, T15, T3.
// Periodic 6-slot schedule (PA..PF), invariant {PA=R15, PB=T15, PC=T3}:
//   m30: (PA,PB)->PD,PE   m60: (PD,PE)->PA[R]   m63: (PA,PC)->PB[T]
//   grad/prox; stage m->PD,PE
//   m2: (PD,PE)->PF[R]    m3: (PF,PE)->PA,PC    m6: (PA,PC)->PD,PE
//   m12: (PD,PE)->PF[R]   m15: (PF,PC)->PA,PB   trace = sum R15.*T15
__global__ __launch_bounds__(256, 2) void dag_iter_kernel(
    const float* __restrict__ adj, float* __restrict__ out, int niter) {
  __shared__ __align__(16) u16 BUF[6 * PL];
  __shared__ float red[4];
  u16* PA = BUF;
  u16* PB = BUF + PL;
  u16* PC = BUF + 2 * PL;
  u16* PD = BUF + 3 * PL;
  u16* PE = BUF + 4 * PL;
  u16* PF = BUF + 5 * PL;

  const int tid = (int)threadIdx.x;
  const int lane = tid & 63;
  const int wv = tid >> 6;
  const int rh4 = (wv >> 1) << 1;  // (rh>>4) = 2*(wv>>1)
  const int ch4 = (wv & 1) << 1;   // (ch>>4) = 2*(wv&1)
  const int l15 = lane & 15;
  const int grp = lane >> 4;
  const int l7 = l15 & 7;
  const int r0 = (tid & 15) << 2;
  const int c0 = (tid >> 4) << 2;

  O o;
#pragma unroll
  for (int q = 0; q < 2; ++q) {
    const int koff = (((q << 2) + grp) ^ l7) << 3;
#pragma unroll
    for (int t = 0; t < 2; ++t) {
      o.ra[t][q] = ((rh4 + t) * 16 + l15) * 64 + koff;
      o.rb[t][q] = ((ch4 + t) * 16 + l15) * 64 + koff;
    }
  }
#pragma unroll
  for (int ti = 0; ti < 2; ++ti)
#pragma unroll
    for (int tj = 0; tj < 2; ++tj) {
      const int a = rh4 + ti;  // row-tile index 0..3
      const int b = ch4 + tj;  // col-tile index 0..3
      // primary tile -> T-plane: row gcol=16b+l15, col-run 16a+4grp
      o.sT[ti][tj] = (16 * b + l15) * 64 +
                     (((2 * a + (grp >> 1)) ^ l7) << 3) + ((grp & 1) << 2);
      // mirror tile -> R-plane: row grow=16a+l15, col-run 16b+4grp
      o.sR[ti][tj] = (16 * a + l15) * 64 +
                     (((2 * b + (grp >> 1)) ^ l7) << 3) + ((grp & 1) << 2);
    }
#pragma unroll
  for (int i = 0; i < 4; ++i) {
    o.prow[i] =
        (r0 + i) * 64 + ((((c0 >> 3) ^ ((r0 + i) & 7))) << 3) + (c0 & 7);
    o.pcol[i] =
        (c0 + i) * 64 + ((((r0 >> 3) ^ ((c0 + i) & 7))) << 3) + (r0 & 7);
  }

  const float* src = adj + (size_t)blockIdx.x * 4096;
  float x[4][4], sc[4][4];
#pragma unroll
  for (int i = 0; i < 4; ++i) {
    f32x4 v = *(const f32x4*)(src + (r0 + i) * 64 + c0);
#pragma unroll
    for (int j = 0; j < 4; ++j) {
      x[i][j] = v[j];
      sc[i][j] = (v[j] > 0.5f) ? v[j] : 0.0f;
    }
  }
  float alpha = 0.0f;

  auto prox = [&](float til[4][4]) {
#pragma unroll
    for (int i = 0; i < 4; ++i)
#pragma unroll
      for (int j = 0; j < 4; ++j) {
        float ax = fabsf(til[i][j]) - 2e-5f;
        float nx = ax > 0.0f ? ax : 0.0f;
        x[i][j] = nx > 1.0f ? 1.0f : nx;
      }
  };
  auto stage = [&]() {  // m = I + x.*x/64 -> PD (R), PE (T)
    float m[4][4];
#pragma unroll
    for (int i = 0; i < 4; ++i)
#pragma unroll
      for (int j = 0; j < 4; ++j)
        m[i][j] = fmaf(x[i][j] * x[i][j], 0.015625f,
                       (r0 + i == c0 + j) ? 1.0f : 0.0f);
#pragma unroll
    for (int i = 0; i < 4; ++i)
      *(uint2*)(PD + o.prow[i]) =
          make_uint2(pk(m[i][0], m[i][1]), pk(m[i][2], m[i][3]));
#pragma unroll
    for (int j = 0; j < 4; ++j)
      *(uint2*)(PE + o.pcol[j]) =
          make_uint2(pk(m[0][j], m[1][j]), pk(m[2][j], m[3][j]));
    __syncthreads();
  };
  auto chain5 = [&]() {  // after stage; leaves PA=R15, PB=T15, PC=T3, red=tr
    mm<true, false>(PD, PE, PF, PF, o);  // m2  -> R only
    mm<true, true>(PF, PE, PA, PC, o);   // m3  = m2*m
    mm<true, true>(PA, PC, PD, PE, o);   // m6  = m3^2
    mm<true, false>(PD, PE, PF, PF, o);  // m12 -> R only
    mm<true, true>(PF, PC, PA, PB, o);   // m15 = m12*m3
    // trace(m^30) = sum_elem R15 .* T15 (identical swizzled addressing)
    float part = 0.0f;
#pragma unroll
    for (int i = 0; i < 4; ++i) {
      uint2 a = *(const uint2*)(PA + o.prow[i]);
      uint2 b = *(const uint2*)(PB + o.prow[i]);
      part = fmaf(rlo(a.x), rlo(b.x), part);
      part = fmaf(rhi(a.x), rhi(b.x), part);
      part = fmaf(rlo(a.y), rlo(b.y), part);
      part = fmaf(rhi(a.y), rhi(b.y), part);
    }
#pragma unroll
    for (int off = 32; off > 0; off >>= 1) part += __shfl_down(part, off);
    if (lane == 0) red[wv] = part;
    // red consumed only after >=1 later barrier (next iter's m30..m63)
  };
  auto gradprox = [&]() {  // uses T63 in PB; alpha from red[]
    float tr = red[0] + red[1] + red[2] + red[3];
    alpha = fmaf(0.01f, tr * 0.015625f - 1.0f, alpha);
    const float a2 = alpha * 0.03125f;  // 2*alpha/64
    float til[4][4];
#pragma unroll
    for (int i = 0; i < 4; ++i) {
      uint2 w = *(const uint2*)(PB + o.prow[i]);
      float pt[4] = {rlo(w.x), rhi(w.x), rlo(w.y), rhi(w.y)};
#pragma unroll
      for (int j = 0; j < 4; ++j) {
        float g = fmaf(a2 * x[i][j], pt[j], -sc[i][j]);
        til[i][j] = fmaf(-0.01f, g, x[i][j]);
      }
    }
    prox(til);
  };

  // ---- iteration 0: alpha == 0 -> grad = -scores ----
  {
    float til[4][4];
#pragma unroll
    for (int i = 0; i < 4; ++i)
#pragma unroll
      for (int j = 0; j < 4; ++j) til[i][j] = fmaf(0.01f, sc[i][j], x[i][j]);
    prox(til);
    stage();
    chain5();
  }
  // ---- iterations 1..48 ----
  for (int it = 0; it < 48; ++it) {
    mm<true, true>(PA, PB, PD, PE, o);   // m30 = m15^2
    mm<true, false>(PD, PE, PA, PA, o);  // m60 -> R only
    mm<false, true>(PA, PC, PB, PB, o);  // m63 = m60*m3 -> T only
    gradprox();
    stage();
    chain5();
  }
  // ---- iteration 49: no trailing trace chain ----
  mm<true, true>(PA, PB, PD, PE, o);
  mm<true, false>(PD, PE, PA, PA, o);
  mm<false, true>(PA, PC, PB, PB, o);
  gradprox();

  float* dst = out + (size_t)blockIdx.x * 4096;
#pragma unroll
  for (int i = 0; i < 4; ++i) {
    f32x4 v;
#pragma unroll
    for (int j = 0; j < 4; ++j) v[j] = (x[i][j] > 0.5f) ? x[i][j] : 0.0f;
    *(f32x4*)(dst + (r0 + i) * 64 + c0) = v;
  }
}

extern "C" void kernel_launch(void* const* d_in, const int* in_sizes, int n_in,
                              void* d_out, int out_size, void* d_ws,
                              size_t ws_size, hipStream_t stream) {
  const float* adj = (const float*)d_in[0];
  float* out = (float*)d_out;
  const int nbatch = in_sizes[0] / 4096;  // 512
  dag_iter_kernel<<<nbatch, 256, 0, stream>>>(adj, out, 50);
}